// Round 11
// baseline (1044.709 us; speedup 1.0000x reference)
//
#include <hip/hip_runtime.h>

#define NPTS   32768
#define DIM    256
#define KCODES 8192
#define TAU    2e-4f

typedef __attribute__((ext_vector_type(8))) short bf16x8;
typedef __attribute__((ext_vector_type(4))) float f32x4;

// direct global->LDS, 16B/lane; LDS dest = wave-uniform base + lane*16
#define GLD(gp, lp)                                                   \
  __builtin_amdgcn_global_load_lds(                                   \
      (const __attribute__((address_space(1))) void*)(gp),            \
      (__attribute__((address_space(3))) void*)(lp), 16, 0, 0)

__device__ __forceinline__ unsigned short f2bf(float x) {  // RNE bf16
  unsigned u = __float_as_uint(x);
  unsigned r = (u + 0x7fffu + ((u >> 16) & 1u)) >> 16;
  return (unsigned short)r;
}
__device__ __forceinline__ float bf2f(unsigned short b) {
  return __uint_as_float(((unsigned)b) << 16);
}

// ---------------- fused hi/lo split + row squared-norms ----------------
__global__ __launch_bounds__(256) void split_norms_kernel(
    const float* __restrict__ src, unsigned short* __restrict__ hi,
    unsigned short* __restrict__ lo, float* __restrict__ norms,
    int* __restrict__ flagcnt) {
  if (flagcnt && blockIdx.x == 0 && threadIdx.x == 0) *flagcnt = 0;
  int row = blockIdx.x * 4 + (threadIdx.x >> 6);
  int lane = threadIdx.x & 63;
  float4 a = reinterpret_cast<const float4*>(src)[row * 64 + lane];
  ushort4 hq, lq;
  hq.x = f2bf(a.x); lq.x = f2bf(a.x - bf2f(hq.x));
  hq.y = f2bf(a.y); lq.y = f2bf(a.y - bf2f(hq.y));
  hq.z = f2bf(a.z); lq.z = f2bf(a.z - bf2f(hq.z));
  hq.w = f2bf(a.w); lq.w = f2bf(a.w - bf2f(hq.w));
  reinterpret_cast<ushort4*>(hi)[row * 64 + lane] = hq;
  reinterpret_cast<ushort4*>(lo)[row * 64 + lane] = lq;
  float sx = a.x * a.x, sy = a.y * a.y, sz = a.z * a.z, sw = a.w * a.w;
  double s = (double)sx + (double)sy + (double)sz + (double)sw;
#pragma unroll
  for (int m = 32; m; m >>= 1) s += __shfl_xor(s, m, 64);
  if (lane == 0) norms[row] = (float)s;
}

// standalone norms (fallback path)
__global__ __launch_bounds__(256) void norms_kernel(const float* __restrict__ src,
                                                    float* __restrict__ dst) {
  int row = blockIdx.x * 4 + (threadIdx.x >> 6);
  int lane = threadIdx.x & 63;
  float4 a = reinterpret_cast<const float4*>(src)[row * 64 + lane];
  float sx = a.x * a.x, sy = a.y * a.y, sz = a.z * a.z, sw = a.w * a.w;
  double s = (double)sx + (double)sy + (double)sz + (double)sw;
#pragma unroll
  for (int m = 32; m; m >>= 1) s += __shfl_xor(s, m, 64);
  if (lane == 0) dst[row] = (float)s;
}

// ---------------- MFMA distance GEMM + per-point top-2 (64x64 wave tile) -----
// 8 waves (2 wrow x 4 wcol), block 128 pts x 256 codes/cc. Staging via
// global_load_lds (16B/lane): no staging VGPRs -> arch regs ~60, combined
// with 64 acc AGPRs <= 128 -> 4 waves/SIMD -> 2 blocks/CU (r10's 140 regs
// gave 1 block/CU). LDS image identical to r10: linear dest + XOR-swizzled
// per-lane GLOBAL source (T21); read side unchanged (inherits r10 pass).
__global__ __launch_bounds__(512, 2) void mfma_argmin_kernel(
    const unsigned short* __restrict__ hh, const unsigned short* __restrict__ hl,
    const unsigned short* __restrict__ ch, const unsigned short* __restrict__ cl,
    const float* __restrict__ h2f, const float* __restrict__ c2f,
    float* __restrict__ bv, int* __restrict__ bi, float* __restrict__ b2o) {
  __shared__ __align__(16) unsigned short As0[4096], As1[4096];   // 8+8 KB
  __shared__ __align__(16) unsigned short Bs0[8192], Bs1[8192];   // 16+16 KB
  __shared__ float tb1[128][4], tb2[128][4];                      // 4 KB
  __shared__ int ti1[128][4];                                     // 2 KB
  const int t = threadIdx.x;
  const int lane = t & 63;
  const int wid = t >> 6;
  const int wrow = wid >> 2, wcol = wid & 3;
  const int b = blockIdx.x;
  const int v = (b & 7) * 64 + (b >> 3);   // XCD-chunked bijective swizzle
  const int sblk = v >> 8, pblk = v & 255;
  const int p0 = pblk * 128;
  const int cbase = sblk * (KCODES / 2);

  // staging source offsets (bytes, 32-bit): row*512 + swizzled_chunk*16.
  // A: wave wid owns chunk wid (rows wid*16 + lane/4). B: chunks 2wid,2wid+1.
  const int alr = (wid << 4) + (lane >> 2);
  const unsigned aoff32 = (unsigned)(p0 + alr) * 512u +
                          (unsigned)(((lane & 3) ^ ((alr >> 1) & 3)) << 4);
  const int blr0 = (wid << 5) + (lane >> 2);
  const int blr1 = blr0 + 16;
  const unsigned boff0 = (unsigned)(cbase + blr0) * 512u +
                         (unsigned)(((lane & 3) ^ ((blr0 >> 1) & 3)) << 4);
  const unsigned boff1 = (unsigned)(cbase + blr1) * 512u +
                         (unsigned)(((lane & 3) ^ ((blr1 >> 1) & 3)) << 4);
  const char* hh_c = (const char*)hh;
  const char* hl_c = (const char*)hl;
  const char* ch_c = (const char*)ch;
  const char* cl_c = (const char*)cl;

  // fragment read offsets (XOR-swizzled, as r10)
  const int flane = lane & 15, fch = lane >> 4;
  int aoff[4], boff[4];
#pragma unroll
  for (int sr = 0; sr < 4; ++sr) {
    int ar = wrow * 64 + sr * 16 + flane;
    aoff[sr] = ar * 64 + ((fch ^ ((ar >> 1) & 3)) << 4);
  }
#pragma unroll
  for (int sc = 0; sc < 4; ++sc) {
    int br = wcol * 64 + sc * 16 + flane;
    boff[sc] = br * 64 + ((fch ^ ((br >> 1) & 3)) << 4);
  }

  // init LDS top-2 state: 512 entries, one per thread
  tb1[t >> 2][t & 3] = 3.4e38f;
  tb2[t >> 2][t & 3] = 3.4e38f;
  ti1[t >> 2][t & 3] = 0;

#pragma unroll 1
  for (int cc = 0; cc < 16; ++cc) {
    f32x4 acc[16];
#pragma unroll
    for (int q = 0; q < 16; ++q) acc[q] = (f32x4){0.f, 0.f, 0.f, 0.f};
    const unsigned bcc = (unsigned)cc * 131072u;  // 256 rows * 512 B

#pragma unroll 1
    for (int dd = 0; dd < 8; ++dd) {
      const unsigned kk = (unsigned)dd * 64u;
      __syncthreads();  // prev stage fully consumed before overwrite
      GLD(hh_c + (aoff32 + kk), (char*)As0 + (wid << 10));
      GLD(hl_c + (aoff32 + kk), (char*)As1 + (wid << 10));
      GLD(ch_c + (boff0 + bcc + kk), (char*)Bs0 + (wid << 11));
      GLD(ch_c + (boff1 + bcc + kk), (char*)Bs0 + (wid << 11) + 1024);
      GLD(cl_c + (boff0 + bcc + kk), (char*)Bs1 + (wid << 11));
      GLD(cl_c + (boff1 + bcc + kk), (char*)Bs1 + (wid << 11) + 1024);
      __syncthreads();  // vmcnt drained -> deposits visible
      bf16x8 ah[4], al[4];
#pragma unroll
      for (int sr = 0; sr < 4; ++sr) {
        ah[sr] = *(const bf16x8*)((const char*)As0 + aoff[sr]);
        al[sr] = *(const bf16x8*)((const char*)As1 + aoff[sr]);
      }
#pragma unroll
      for (int sc = 0; sc < 4; ++sc) {
        bf16x8 bh = *(const bf16x8*)((const char*)Bs0 + boff[sc]);
        bf16x8 bl = *(const bf16x8*)((const char*)Bs1 + boff[sc]);
#pragma unroll
        for (int sr = 0; sr < 4; ++sr) {
          acc[sc * 4 + sr] = __builtin_amdgcn_mfma_f32_16x16x32_bf16(ah[sr], bh, acc[sc * 4 + sr], 0, 0, 0);
          acc[sc * 4 + sr] = __builtin_amdgcn_mfma_f32_16x16x32_bf16(al[sr], bh, acc[sc * 4 + sr], 0, 0, 0);
          acc[sc * 4 + sr] = __builtin_amdgcn_mfma_f32_16x16x32_bf16(ah[sr], bl, acc[sc * 4 + sr], 0, 0, 0);
        }
      }
    }
    // epilogue: numpy-fp32 scores, per-slot top-2, lane-merge, LDS RMW
    int cols[4];
    float c2v[4];
#pragma unroll
    for (int sc = 0; sc < 4; ++sc) {
      cols[sc] = cbase + cc * 256 + wcol * 64 + sc * 16 + flane;
      c2v[sc] = c2f[cols[sc]];
    }
#pragma unroll
    for (int slot = 0; slot < 16; ++slot) {
      const int sr = slot >> 2, r = slot & 3;
      const float h2v = h2f[p0 + wrow * 64 + sr * 16 + fch * 4 + r];
      float b1 = 3.4e38f, b2 = 3.4e38f;
      int i1 = 0;
#pragma unroll
      for (int sc = 0; sc < 4; ++sc) {
        float A2 = h2v + c2v[sc];                       // fl32(h2+c2)
        float s = fmaf(-2.f, acc[sc * 4 + sr][r], A2);  // fl32(A - 2*dot)
        if (s < b1) { b2 = b1; b1 = s; i1 = cols[sc]; }
        else if (s < b2) b2 = s;
      }
#pragma unroll
      for (int m = 1; m <= 8; m <<= 1) {
        float ob1 = __shfl_xor(b1, m, 64);
        int oi1 = __shfl_xor(i1, m, 64);
        float ob2 = __shfl_xor(b2, m, 64);
        float loser = fmaxf(b1, ob1);
        float nb2 = fminf(fminf(b2, ob2), loser);
        if (ob1 < b1 || (ob1 == b1 && oi1 < i1)) { b1 = ob1; i1 = oi1; }
        b2 = nb2;
      }
      if (flane == 0) {
        int pl = wrow * 64 + sr * 16 + fch * 4 + r;
        float gb1 = tb1[pl][wcol], gb2 = tb2[pl][wcol];
        int gi1 = ti1[pl][wcol];
        float loser = fmaxf(gb1, b1);
        float nb2 = fminf(fminf(gb2, b2), loser);
        if (b1 < gb1 || (b1 == gb1 && i1 < gi1)) { gb1 = b1; gi1 = i1; }
        tb1[pl][wcol] = gb1;
        ti1[pl][wcol] = gi1;
        tb2[pl][wcol] = nb2;
      }
    }
  }
  __syncthreads();
  // writeout: merge 4 wcol entries per point, idx tiebreak
  if (t < 128) {
    float b1 = tb1[t][0], b2 = tb2[t][0];
    int i1 = ti1[t][0];
#pragma unroll
    for (int w = 1; w < 4; ++w) {
      float nb1 = tb1[t][w], nb2v = tb2[t][w];
      int ni1 = ti1[t][w];
      float loser = fmaxf(b1, nb1);
      float m2 = fminf(fminf(b2, nb2v), loser);
      if (nb1 < b1 || (nb1 == b1 && ni1 < i1)) { b1 = nb1; i1 = ni1; }
      b2 = m2;
    }
    int p = p0 + t;
    bv[sblk * NPTS + p] = b1;
    bi[sblk * NPTS + p] = i1;
    b2o[sblk * NPTS + p] = b2;
  }
}

// ---------------- merge 2 slices + flag near-ties ----------------
__global__ __launch_bounds__(256) void merge_flag_kernel(
    const float* __restrict__ bv, const int* __restrict__ bi,
    const float* __restrict__ b2o, int* __restrict__ idx,
    float* __restrict__ out_idx_f, int* __restrict__ flagcnt,
    int* __restrict__ flaglist) {
  int p = blockIdx.x * 256 + threadIdx.x;
  float b1 = bv[p]; int i1 = bi[p]; float b2 = b2o[p];
  {
    float pb1 = bv[NPTS + p];
    int pi1 = bi[NPTS + p];
    float pb2 = b2o[NPTS + p];
    float loser = fmaxf(b1, pb1);
    float nb2 = fminf(fminf(b2, pb2), loser);
    if (pb1 < b1 || (pb1 == b1 && pi1 < i1)) { b1 = pb1; i1 = pi1; }
    b2 = nb2;
  }
  idx[p] = i1;
  out_idx_f[p] = (float)i1;
  if (b2 - b1 < TAU) { int s = atomicAdd(flagcnt, 1); flaglist[s] = p; }
}

// ---------------- exact numpy-semantics re-argmin for flagged points ----------
__global__ __launch_bounds__(256) void refine_kernel(
    const float* __restrict__ h, const float* __restrict__ cb,
    const float* __restrict__ h2f, const float* __restrict__ c2f,
    const int* __restrict__ flagcnt, const int* __restrict__ flaglist,
    int* __restrict__ idx, float* __restrict__ out_idx_f) {
  __shared__ float hrow[DIM];
  __shared__ float rb[256];
  __shared__ int ri[256];
  const int n = *flagcnt;
  for (int e = blockIdx.x; e < n; e += gridDim.x) {
    const int p = flaglist[e];
    __syncthreads();
    if (threadIdx.x < DIM / 4)
      reinterpret_cast<float4*>(hrow)[threadIdx.x] =
          reinterpret_cast<const float4*>(h + p * DIM)[threadIdx.x];
    __syncthreads();
    const float h2 = h2f[p];
    float b1 = 3.4e38f;
    int i1 = 0x7fffffff;
    for (int c = threadIdx.x; c < KCODES; c += 256) {
      const float4* crow = reinterpret_cast<const float4*>(cb + c * DIM);
      float dot = 0.f;
#pragma unroll 16
      for (int d4 = 0; d4 < DIM / 4; ++d4) {
        float4 cv = crow[d4];
        dot = fmaf(hrow[4 * d4 + 0], cv.x, dot);
        dot = fmaf(hrow[4 * d4 + 1], cv.y, dot);
        dot = fmaf(hrow[4 * d4 + 2], cv.z, dot);
        dot = fmaf(hrow[4 * d4 + 3], cv.w, dot);
      }
      float A = h2 + c2f[c];
      float s = fmaf(-2.f, dot, A);
      if (s < b1) { b1 = s; i1 = c; }
    }
    rb[threadIdx.x] = b1;
    ri[threadIdx.x] = i1;
    __syncthreads();
    for (int step = 128; step; step >>= 1) {
      if (threadIdx.x < step) {
        float ob = rb[threadIdx.x + step];
        int oi = ri[threadIdx.x + step];
        if (ob < rb[threadIdx.x] || (ob == rb[threadIdx.x] && oi < ri[threadIdx.x])) {
          rb[threadIdx.x] = ob;
          ri[threadIdx.x] = oi;
        }
      }
      __syncthreads();
    }
    if (threadIdx.x == 0) { idx[p] = ri[0]; out_idx_f[p] = (float)ri[0]; }
  }
}

// ---------------- fallback: r7 fp32 argmin (8x8 tile) + 2-way merge ----------
__global__ __launch_bounds__(512, 2) void argmin_fp32_kernel(
    const float* __restrict__ h, const float* __restrict__ cb,
    const float* __restrict__ h2f, const float* __restrict__ c2f,
    float* __restrict__ bestval, int* __restrict__ bestidx) {
  __shared__ float hs[16][132];
  __shared__ float cs[16][260];
  const int t = threadIdx.x;
  const int ct = t & 31;
  const int pt = t >> 5;
  const int b = blockIdx.x;
  const int v = (b & 7) * 64 + (b >> 3);
  const int sblk = v >> 8;
  const int pblk = v & 255;
  const int p0 = pblk * 128;
  const int cbase = sblk * (KCODES / 2);
  float best[8]; int besti[8]; float h2r[8];
#pragma unroll
  for (int i = 0; i < 8; ++i) {
    best[i] = 3.4e38f; besti[i] = 0;
    h2r[i] = h2f[p0 + pt * 4 + ((i >> 2) << 6) + (i & 3)];
  }
#pragma unroll 1
  for (int cc = 0; cc < (KCODES / 2) / 256; ++cc) {
    const int c0 = cbase + cc * 256;
    float dot[8][8];
#pragma unroll
    for (int i = 0; i < 8; ++i)
#pragma unroll
      for (int j = 0; j < 8; ++j) dot[i][j] = 0.f;
#pragma unroll 1
    for (int dd = 0; dd < DIM / 16; ++dd) {
      const int d0 = dd * 16;
      {
        int p = t >> 2, k4 = (t & 3) << 2;
        float4 w = *reinterpret_cast<const float4*>(h + (p0 + p) * DIM + d0 + k4);
        hs[k4 + 0][p] = w.x; hs[k4 + 1][p] = w.y;
        hs[k4 + 2][p] = w.z; hs[k4 + 3][p] = w.w;
      }
#pragma unroll
      for (int l = 0; l < 2; ++l) {
        int F = t + l * 512;
        int c = F >> 2, k4 = (F & 3) << 2;
        float4 w = *reinterpret_cast<const float4*>(cb + (c0 + c) * DIM + d0 + k4);
        cs[k4 + 0][c] = w.x; cs[k4 + 1][c] = w.y;
        cs[k4 + 2][c] = w.z; cs[k4 + 3][c] = w.w;
      }
      __syncthreads();
#pragma unroll
      for (int k = 0; k < 16; ++k) {
        float hv[8], cv[8];
        *reinterpret_cast<float4*>(&hv[0]) = *reinterpret_cast<const float4*>(&hs[k][pt * 4]);
        *reinterpret_cast<float4*>(&hv[4]) = *reinterpret_cast<const float4*>(&hs[k][pt * 4 + 64]);
        *reinterpret_cast<float4*>(&cv[0]) = *reinterpret_cast<const float4*>(&cs[k][ct * 4]);
        *reinterpret_cast<float4*>(&cv[4]) = *reinterpret_cast<const float4*>(&cs[k][ct * 4 + 128]);
#pragma unroll
        for (int i = 0; i < 8; ++i)
#pragma unroll
          for (int j = 0; j < 8; ++j) dot[i][j] = fmaf(hv[i], cv[j], dot[i][j]);
      }
      __syncthreads();
    }
#pragma unroll
    for (int j = 0; j < 8; ++j) {
      int cl = c0 + (ct << 2) + ((j >> 2) << 7) + (j & 3);
      float cc2 = c2f[cl];
#pragma unroll
      for (int i = 0; i < 8; ++i) {
        float A = h2r[i] + cc2;
        float s = A - 2.0f * dot[i][j];
        if (s < best[i]) { best[i] = s; besti[i] = cl; }
      }
    }
  }
#pragma unroll
  for (int i = 0; i < 8; ++i) {
    float b1 = best[i]; int i1 = besti[i];
#pragma unroll
    for (int m = 16; m; m >>= 1) {
      float so = __shfl_xor(b1, m, 64);
      int io = __shfl_xor(i1, m, 64);
      if (so < b1 || (so == b1 && io < i1)) { b1 = so; i1 = io; }
    }
    if (ct == 0) {
      int p = p0 + pt * 4 + ((i >> 2) << 6) + (i & 3);
      bestval[sblk * NPTS + p] = b1;
      bestidx[sblk * NPTS + p] = i1;
    }
  }
}

__global__ __launch_bounds__(256) void merge2_kernel(
    const float* __restrict__ bestval, const int* __restrict__ bestidx,
    int* __restrict__ idx, float* __restrict__ out_idx_f) {
  int p = blockIdx.x * 256 + threadIdx.x;
  float v0 = bestval[p], v1 = bestval[NPTS + p];
  int i0 = bestidx[p], i1 = bestidx[NPTS + p];
  int w = (v1 < v0) ? i1 : i0;
  idx[p] = w;
  out_idx_f[p] = (float)w;
}

// ---------------- gather + finalize ----------------
__global__ __launch_bounds__(256) void gather_kernel(
    const float* __restrict__ h, const float* __restrict__ cb,
    const unsigned char* __restrict__ maskb, const int* __restrict__ idx,
    float* __restrict__ zq, float* __restrict__ partial) {
  int p = blockIdx.x * 4 + (threadIdx.x >> 6);
  int lane = threadIdx.x & 63;
  int ci = idx[p];
  float4 hv = reinterpret_cast<const float4*>(h)[p * (DIM / 4) + lane];
  float4 zv = reinterpret_cast<const float4*>(cb)[ci * (DIM / 4) + lane];
  float4 q;
  q.x = hv.x + (zv.x - hv.x);
  q.y = hv.y + (zv.y - hv.y);
  q.z = hv.z + (zv.z - hv.z);
  q.w = hv.w + (zv.w - hv.w);
  reinterpret_cast<float4*>(zq)[p * (DIM / 4) + lane] = q;
  float dx = hv.x - zv.x, dy = hv.y - zv.y, dz = hv.z - zv.z, dw = hv.w - zv.w;
  float s = (maskb[p] != 0) ? (dx * dx + dy * dy + dz * dz + dw * dw) : 0.f;
#pragma unroll
  for (int m = 32; m; m >>= 1) s += __shfl_xor(s, m, 64);
  __shared__ float bs[4];
  if (lane == 0) bs[threadIdx.x >> 6] = s;
  __syncthreads();
  if (threadIdx.x == 0) partial[blockIdx.x] = bs[0] + bs[1] + bs[2] + bs[3];
}

__global__ __launch_bounds__(256) void finalize_kernel(
    const float* __restrict__ partial, const unsigned char* __restrict__ maskb,
    float* __restrict__ out_losses) {
  __shared__ float red[256];
  __shared__ int redi[256];
  float s = 0.f;
  for (int i = threadIdx.x; i < NPTS / 4; i += 256) s += partial[i];
  int cnt = 0;
  for (int i = threadIdx.x; i < NPTS; i += 256) cnt += (maskb[i] != 0);
  red[threadIdx.x] = s;
  redi[threadIdx.x] = cnt;
  __syncthreads();
  for (int step = 128; step; step >>= 1) {
    if (threadIdx.x < step) {
      red[threadIdx.x] += red[threadIdx.x + step];
      redi[threadIdx.x] += redi[threadIdx.x + step];
    }
    __syncthreads();
  }
  if (threadIdx.x == 0) {
    float denom = (float)redi[0] * (float)DIM + 1e-8f;
    float loss = red[0] / denom;
    out_losses[0] = loss;
    out_losses[1] = loss;
  }
}

extern "C" void kernel_launch(void* const* d_in, const int* in_sizes, int n_in,
                              void* d_out, int out_size, void* d_ws, size_t ws_size,
                              hipStream_t stream) {
  const float* h = (const float*)d_in[0];
  const unsigned char* maskb = (const unsigned char*)d_in[1];
  const float* cb = (const float*)d_in[2];

  float* out = (float*)d_out;
  float* zq = out;
  float* out_idx_f = out + NPTS * DIM;
  float* out_losses = out + NPTS * DIM + NPTS;

  char* ws = (char*)d_ws;
  const size_t REQ = 44040192ULL;  // 42 MB

  if (ws_size >= REQ) {
    float* h2f = (float*)(ws + 0);                    // 128K
    float* c2f = (float*)(ws + 131072);               // 32K
    float* bv = (float*)(ws + 163840);                // 256K used
    int* bi = (int*)(ws + 688128);                    // 256K used
    float* b2o = (float*)(ws + 1212416);              // 256K used
    int* idx = (int*)(ws + 1736704);                  // 128K
    float* partial = (float*)(ws + 1867776);          // 32K
    int* flagcnt = (int*)(ws + 1900544);              // 4 (+pad)
    int* flaglist = (int*)(ws + 1904640);             // 128K
    unsigned short* hh = (unsigned short*)(ws + 2097152);    // 16M
    unsigned short* hl = (unsigned short*)(ws + 18874368);   // 16M
    unsigned short* chh = (unsigned short*)(ws + 35651584);  // 4M
    unsigned short* cll = (unsigned short*)(ws + 39845888);  // 4M

    hipLaunchKernelGGL(split_norms_kernel, dim3(NPTS / 4), dim3(256), 0, stream,
                       h, hh, hl, h2f, flagcnt);
    hipLaunchKernelGGL(split_norms_kernel, dim3(KCODES / 4), dim3(256), 0, stream,
                       cb, chh, cll, c2f, (int*)nullptr);
    hipLaunchKernelGGL(mfma_argmin_kernel, dim3(512), dim3(512), 0, stream,
                       hh, hl, chh, cll, h2f, c2f, bv, bi, b2o);
    hipLaunchKernelGGL(merge_flag_kernel, dim3(NPTS / 256), dim3(256), 0, stream,
                       bv, bi, b2o, idx, out_idx_f, flagcnt, flaglist);
    hipLaunchKernelGGL(refine_kernel, dim3(512), dim3(256), 0, stream,
                       h, cb, h2f, c2f, flagcnt, flaglist, idx, out_idx_f);
    hipLaunchKernelGGL(gather_kernel, dim3(NPTS / 4), dim3(256), 0, stream,
                       h, cb, maskb, idx, zq, partial);
    hipLaunchKernelGGL(finalize_kernel, dim3(1), dim3(256), 0, stream,
                       partial, maskb, out_losses);
  } else {
    float* h2f = (float*)(ws + 0);
    float* c2f = (float*)(ws + (128 << 10));
    float* bestval = (float*)(ws + (160 << 10));
    int* bestidx = (int*)(ws + (416 << 10));
    int* idx = (int*)(ws + (672 << 10));
    float* partial = (float*)(ws + (800 << 10));

    hipLaunchKernelGGL(norms_kernel, dim3(NPTS / 4), dim3(256), 0, stream, h, h2f);
    hipLaunchKernelGGL(norms_kernel, dim3(KCODES / 4), dim3(256), 0, stream, cb, c2f);
    hipLaunchKernelGGL(argmin_fp32_kernel, dim3(512), dim3(512), 0, stream,
                       h, cb, h2f, c2f, bestval, bestidx);
    hipLaunchKernelGGL(merge2_kernel, dim3(NPTS / 256), dim3(256), 0, stream,
                       bestval, bestidx, idx, out_idx_f);
    hipLaunchKernelGGL(gather_kernel, dim3(NPTS / 4), dim3(256), 0, stream,
                       h, cb, maskb, idx, zq, partial);
    hipLaunchKernelGGL(finalize_kernel, dim3(1), dim3(256), 0, stream,
                       partial, maskb, out_losses);
  }
}

// Round 12
// 891.095 us; speedup vs baseline: 1.1724x; 1.1724x over previous
//
#include <hip/hip_runtime.h>

#define NPTS   32768
#define DIM    256
#define KCODES 8192
#define TAU    2e-4f

typedef __attribute__((ext_vector_type(8))) short bf16x8;
typedef __attribute__((ext_vector_type(4))) float f32x4;

__device__ __forceinline__ unsigned short f2bf(float x) {  // RNE bf16
  unsigned u = __float_as_uint(x);
  unsigned r = (u + 0x7fffu + ((u >> 16) & 1u)) >> 16;
  return (unsigned short)r;
}
__device__ __forceinline__ float bf2f(unsigned short b) {
  return __uint_as_float(((unsigned)b) << 16);
}

// ---------------- fused hi/lo split + row squared-norms ----------------
__global__ __launch_bounds__(256) void split_norms_kernel(
    const float* __restrict__ src, unsigned short* __restrict__ hi,
    unsigned short* __restrict__ lo, float* __restrict__ norms,
    int* __restrict__ flagcnt) {
  if (flagcnt && blockIdx.x == 0 && threadIdx.x == 0) *flagcnt = 0;
  int row = blockIdx.x * 4 + (threadIdx.x >> 6);
  int lane = threadIdx.x & 63;
  float4 a = reinterpret_cast<const float4*>(src)[row * 64 + lane];
  ushort4 hq, lq;
  hq.x = f2bf(a.x); lq.x = f2bf(a.x - bf2f(hq.x));
  hq.y = f2bf(a.y); lq.y = f2bf(a.y - bf2f(hq.y));
  hq.z = f2bf(a.z); lq.z = f2bf(a.z - bf2f(hq.z));
  hq.w = f2bf(a.w); lq.w = f2bf(a.w - bf2f(hq.w));
  reinterpret_cast<ushort4*>(hi)[row * 64 + lane] = hq;
  reinterpret_cast<ushort4*>(lo)[row * 64 + lane] = lq;
  float sx = a.x * a.x, sy = a.y * a.y, sz = a.z * a.z, sw = a.w * a.w;
  double s = (double)sx + (double)sy + (double)sz + (double)sw;
#pragma unroll
  for (int m = 32; m; m >>= 1) s += __shfl_xor(s, m, 64);
  if (lane == 0) norms[row] = (float)s;
}

// standalone norms (fallback path)
__global__ __launch_bounds__(256) void norms_kernel(const float* __restrict__ src,
                                                    float* __restrict__ dst) {
  int row = blockIdx.x * 4 + (threadIdx.x >> 6);
  int lane = threadIdx.x & 63;
  float4 a = reinterpret_cast<const float4*>(src)[row * 64 + lane];
  float sx = a.x * a.x, sy = a.y * a.y, sz = a.z * a.z, sw = a.w * a.w;
  double s = (double)sx + (double)sy + (double)sz + (double)sw;
#pragma unroll
  for (int m = 32; m; m >>= 1) s += __shfl_xor(s, m, 64);
  if (lane == 0) dst[row] = (float)s;
}

// ---------------- MFMA distance GEMM + per-point top-2 ----------------
// r8's proven geometry (8 waves 4x2, 128pt x 128codes/cc, 32x64 wave tile,
// 32 acc AGPRs, 60 arch VGPRs -> 2 blocks/CU). ONE change vs r8: loads for
// stage s+1 are issued AFTER the second barrier, BEFORE the MFMA block of
// stage s -- global latency hides under the wave's own MFMAs instead of
// being exposed between barrier-1 and the ds_write. +16 held VGPRs ->
// ~76+32=108 combined <= 128, co-residency retained.
__global__ __launch_bounds__(512, 2) void mfma_argmin_kernel(
    const unsigned short* __restrict__ hh, const unsigned short* __restrict__ hl,
    const unsigned short* __restrict__ ch, const unsigned short* __restrict__ cl,
    const float* __restrict__ h2f, const float* __restrict__ c2f,
    float* __restrict__ bv, int* __restrict__ bi, float* __restrict__ b2o) {
  __shared__ __align__(16) unsigned short As0[4096], As1[4096], Bs0[4096], Bs1[4096];
  const int t = threadIdx.x;
  const int lane = t & 63;
  const int wid = t >> 6;
  const int wrow = wid >> 1, wcol = wid & 1;
  const int b = blockIdx.x;
  const int v = (b & 7) * 64 + (b >> 3);   // XCD-chunked bijective swizzle
  const int sblk = v >> 8, pblk = v & 255;
  const int p0 = pblk * 128;
  const int cbase = sblk * (KCODES / 2);

  // staging: thread t owns one 16B block per tile per stage
  const int strow = t >> 2, stblk = t & 3;
  const int stoff = strow * 64 + ((stblk ^ ((strow >> 1) & 3)) << 4);
  const uint4* hh4 = (const uint4*)hh;
  const uint4* hl4 = (const uint4*)hl;
  const uint4* ch4 = (const uint4*)ch;
  const uint4* cl4 = (const uint4*)cl;
  const int arow4 = (p0 + strow) * 32 + stblk;      // + (s&7)*4
  const int bbase4 = (cbase + strow) * 32 + stblk;  // + (s>>3)*4096 + (s&7)*4

  // fragment read offsets (A rows: wrow*32 + sr*16 + (lane&15); k-blk = lane>>4)
  const int ablk = lane >> 4;
  const int ar0 = wrow * 32 + (lane & 15);
  const int ar1 = ar0 + 16;
  const int aoff0 = ar0 * 64 + ((ablk ^ ((ar0 >> 1) & 3)) << 4);
  const int aoff1 = ar1 * 64 + ((ablk ^ ((ar1 >> 1) & 3)) << 4);
  int boff[4];
#pragma unroll
  for (int sc = 0; sc < 4; ++sc) {
    int cr = wcol * 64 + sc * 16 + (lane & 15);
    boff[sc] = cr * 64 + ((ablk ^ ((cr >> 1) & 3)) << 4);
  }

  float h2r[8];
#pragma unroll
  for (int sr = 0; sr < 2; ++sr)
#pragma unroll
    for (int r = 0; r < 4; ++r)
      h2r[sr * 4 + r] = h2f[p0 + wrow * 32 + sr * 16 + ((lane >> 4) << 2) + r];

  float sb1[8], sbt2[8];
  int si1[8];
#pragma unroll
  for (int q = 0; q < 8; ++q) { sb1[q] = 3.4e38f; sbt2[q] = 3.4e38f; si1[q] = 0; }

  // prologue: loads for stage 0
  uint4 va0 = hh4[arow4], va1 = hl4[arow4];
  uint4 vb0 = ch4[bbase4], vb1 = cl4[bbase4];

#pragma unroll 1
  for (int cc = 0; cc < 32; ++cc) {
    f32x4 acc[8];
#pragma unroll
    for (int q = 0; q < 8; ++q) acc[q] = (f32x4){0.f, 0.f, 0.f, 0.f};

#pragma unroll
    for (int dd = 0; dd < 8; ++dd) {
      __syncthreads();  // previous stage fully consumed
      *(uint4*)((char*)As0 + stoff) = va0;   // implicit vmcnt wait
      *(uint4*)((char*)As1 + stoff) = va1;
      *(uint4*)((char*)Bs0 + stoff) = vb0;
      *(uint4*)((char*)Bs1 + stoff) = vb1;
      __syncthreads();  // deposits visible
      // issue loads for stage s+1 -- latency hides under this stage's MFMAs
      int s1 = cc * 8 + dd + 1;
      if (s1 > 255) s1 = 255;
      const int la = arow4 + (s1 & 7) * 4;
      const int lb = bbase4 + (s1 >> 3) * 4096 + (s1 & 7) * 4;
      va0 = hh4[la]; va1 = hl4[la];
      vb0 = ch4[lb]; vb1 = cl4[lb];
      // MFMA from LDS
      bf16x8 a0h = *(const bf16x8*)((const char*)As0 + aoff0);
      bf16x8 a0l = *(const bf16x8*)((const char*)As1 + aoff0);
      bf16x8 a1h = *(const bf16x8*)((const char*)As0 + aoff1);
      bf16x8 a1l = *(const bf16x8*)((const char*)As1 + aoff1);
#pragma unroll
      for (int sc = 0; sc < 4; ++sc) {
        bf16x8 bh = *(const bf16x8*)((const char*)Bs0 + boff[sc]);
        bf16x8 bl = *(const bf16x8*)((const char*)Bs1 + boff[sc]);
        acc[sc] = __builtin_amdgcn_mfma_f32_16x16x32_bf16(a0h, bh, acc[sc], 0, 0, 0);
        acc[sc] = __builtin_amdgcn_mfma_f32_16x16x32_bf16(a0l, bh, acc[sc], 0, 0, 0);
        acc[sc] = __builtin_amdgcn_mfma_f32_16x16x32_bf16(a0h, bl, acc[sc], 0, 0, 0);
        acc[4 + sc] = __builtin_amdgcn_mfma_f32_16x16x32_bf16(a1h, bh, acc[4 + sc], 0, 0, 0);
        acc[4 + sc] = __builtin_amdgcn_mfma_f32_16x16x32_bf16(a1l, bh, acc[4 + sc], 0, 0, 0);
        acc[4 + sc] = __builtin_amdgcn_mfma_f32_16x16x32_bf16(a1h, bl, acc[4 + sc], 0, 0, 0);
      }
    }
    // epilogue: numpy-fp32 scores + running top-2 (ascending code order)
#pragma unroll
    for (int sc = 0; sc < 4; ++sc) {
      int col = cbase + cc * 128 + wcol * 64 + sc * 16 + (lane & 15);
      float c2v = c2f[col];
#pragma unroll
      for (int sr = 0; sr < 2; ++sr)
#pragma unroll
        for (int r = 0; r < 4; ++r) {
          int slot = sr * 4 + r;
          float A = h2r[slot] + c2v;                       // fl32(h2+c2)
          float sv = fmaf(-2.f, acc[sr * 4 + sc][r], A);   // fl32(A - 2*dot)
          if (sv < sb1[slot]) { sbt2[slot] = sb1[slot]; sb1[slot] = sv; si1[slot] = col; }
          else if (sv < sbt2[slot]) sbt2[slot] = sv;
        }
    }
  }
  // cross-lane top-2 merge over the 16 col-lanes (lowest-index tiebreak on b1)
#pragma unroll
  for (int slot = 0; slot < 8; ++slot) {
    float b1 = sb1[slot]; int i1 = si1[slot]; float b2 = sbt2[slot];
#pragma unroll
    for (int m = 1; m <= 8; m <<= 1) {
      float ob1 = __shfl_xor(b1, m, 64);
      int oi1 = __shfl_xor(i1, m, 64);
      float ob2 = __shfl_xor(b2, m, 64);
      float loser = fmaxf(b1, ob1);
      float nb2 = fminf(fminf(b2, ob2), loser);
      if (ob1 < b1 || (ob1 == b1 && oi1 < i1)) { b1 = ob1; i1 = oi1; }
      b2 = nb2;
    }
    if ((lane & 15) == 0) {
      int p = p0 + wrow * 32 + (slot >> 2) * 16 + ((lane >> 4) << 2) + (slot & 3);
      int part = sblk * 2 + wcol;
      bv[part * NPTS + p] = b1;
      bi[part * NPTS + p] = i1;
      b2o[part * NPTS + p] = b2;
    }
  }
}

// ---------------- merge 4 partials + flag near-ties ----------------
__global__ __launch_bounds__(256) void merge_flag_kernel(
    const float* __restrict__ bv, const int* __restrict__ bi,
    const float* __restrict__ b2o, int* __restrict__ idx,
    float* __restrict__ out_idx_f, int* __restrict__ flagcnt,
    int* __restrict__ flaglist) {
  int p = blockIdx.x * 256 + threadIdx.x;
  float b1 = bv[p]; int i1 = bi[p]; float b2 = b2o[p];
#pragma unroll
  for (int part = 1; part < 4; ++part) {
    float pb1 = bv[part * NPTS + p];
    int pi1 = bi[part * NPTS + p];
    float pb2 = b2o[part * NPTS + p];
    float loser = fmaxf(b1, pb1);
    float nb2 = fminf(fminf(b2, pb2), loser);
    if (pb1 < b1 || (pb1 == b1 && pi1 < i1)) { b1 = pb1; i1 = pi1; }
    b2 = nb2;
  }
  idx[p] = i1;
  out_idx_f[p] = (float)i1;
  if (b2 - b1 < TAU) { int s = atomicAdd(flagcnt, 1); flaglist[s] = p; }
}

// ---------------- exact numpy-semantics re-argmin for flagged points ----------
__global__ __launch_bounds__(256) void refine_kernel(
    const float* __restrict__ h, const float* __restrict__ cb,
    const float* __restrict__ h2f, const float* __restrict__ c2f,
    const int* __restrict__ flagcnt, const int* __restrict__ flaglist,
    int* __restrict__ idx, float* __restrict__ out_idx_f) {
  __shared__ float hrow[DIM];
  __shared__ float rb[256];
  __shared__ int ri[256];
  const int n = *flagcnt;
  for (int e = blockIdx.x; e < n; e += gridDim.x) {
    const int p = flaglist[e];
    __syncthreads();
    if (threadIdx.x < DIM / 4)
      reinterpret_cast<float4*>(hrow)[threadIdx.x] =
          reinterpret_cast<const float4*>(h + p * DIM)[threadIdx.x];
    __syncthreads();
    const float h2 = h2f[p];
    float b1 = 3.4e38f;
    int i1 = 0x7fffffff;
    for (int c = threadIdx.x; c < KCODES; c += 256) {
      const float4* crow = reinterpret_cast<const float4*>(cb + c * DIM);
      float dot = 0.f;
#pragma unroll 16
      for (int d4 = 0; d4 < DIM / 4; ++d4) {
        float4 cv = crow[d4];
        dot = fmaf(hrow[4 * d4 + 0], cv.x, dot);
        dot = fmaf(hrow[4 * d4 + 1], cv.y, dot);
        dot = fmaf(hrow[4 * d4 + 2], cv.z, dot);
        dot = fmaf(hrow[4 * d4 + 3], cv.w, dot);
      }
      float A = h2 + c2f[c];
      float s = fmaf(-2.f, dot, A);
      if (s < b1) { b1 = s; i1 = c; }
    }
    rb[threadIdx.x] = b1;
    ri[threadIdx.x] = i1;
    __syncthreads();
    for (int step = 128; step; step >>= 1) {
      if (threadIdx.x < step) {
        float ob = rb[threadIdx.x + step];
        int oi = ri[threadIdx.x + step];
        if (ob < rb[threadIdx.x] || (ob == rb[threadIdx.x] && oi < ri[threadIdx.x])) {
          rb[threadIdx.x] = ob;
          ri[threadIdx.x] = oi;
        }
      }
      __syncthreads();
    }
    if (threadIdx.x == 0) { idx[p] = ri[0]; out_idx_f[p] = (float)ri[0]; }
  }
}

// ---------------- fallback: r7 fp32 argmin (8x8 tile) + 2-way merge ----------
__global__ __launch_bounds__(512, 2) void argmin_fp32_kernel(
    const float* __restrict__ h, const float* __restrict__ cb,
    const float* __restrict__ h2f, const float* __restrict__ c2f,
    float* __restrict__ bestval, int* __restrict__ bestidx) {
  __shared__ float hs[16][132];
  __shared__ float cs[16][260];
  const int t = threadIdx.x;
  const int ct = t & 31;
  const int pt = t >> 5;
  const int b = blockIdx.x;
  const int v = (b & 7) * 64 + (b >> 3);
  const int sblk = v >> 8;
  const int pblk = v & 255;
  const int p0 = pblk * 128;
  const int cbase = sblk * (KCODES / 2);
  float best[8]; int besti[8]; float h2r[8];
#pragma unroll
  for (int i = 0; i < 8; ++i) {
    best[i] = 3.4e38f; besti[i] = 0;
    h2r[i] = h2f[p0 + pt * 4 + ((i >> 2) << 6) + (i & 3)];
  }
#pragma unroll 1
  for (int cc = 0; cc < (KCODES / 2) / 256; ++cc) {
    const int c0 = cbase + cc * 256;
    float dot[8][8];
#pragma unroll
    for (int i = 0; i < 8; ++i)
#pragma unroll
      for (int j = 0; j < 8; ++j) dot[i][j] = 0.f;
#pragma unroll 1
    for (int dd = 0; dd < DIM / 16; ++dd) {
      const int d0 = dd * 16;
      {
        int p = t >> 2, k4 = (t & 3) << 2;
        float4 w = *reinterpret_cast<const float4*>(h + (p0 + p) * DIM + d0 + k4);
        hs[k4 + 0][p] = w.x; hs[k4 + 1][p] = w.y;
        hs[k4 + 2][p] = w.z; hs[k4 + 3][p] = w.w;
      }
#pragma unroll
      for (int l = 0; l < 2; ++l) {
        int F = t + l * 512;
        int c = F >> 2, k4 = (F & 3) << 2;
        float4 w = *reinterpret_cast<const float4*>(cb + (c0 + c) * DIM + d0 + k4);
        cs[k4 + 0][c] = w.x; cs[k4 + 1][c] = w.y;
        cs[k4 + 2][c] = w.z; cs[k4 + 3][c] = w.w;
      }
      __syncthreads();
#pragma unroll
      for (int k = 0; k < 16; ++k) {
        float hv[8], cv[8];
        *reinterpret_cast<float4*>(&hv[0]) = *reinterpret_cast<const float4*>(&hs[k][pt * 4]);
        *reinterpret_cast<float4*>(&hv[4]) = *reinterpret_cast<const float4*>(&hs[k][pt * 4 + 64]);
        *reinterpret_cast<float4*>(&cv[0]) = *reinterpret_cast<const float4*>(&cs[k][ct * 4]);
        *reinterpret_cast<float4*>(&cv[4]) = *reinterpret_cast<const float4*>(&cs[k][ct * 4 + 128]);
#pragma unroll
        for (int i = 0; i < 8; ++i)
#pragma unroll
          for (int j = 0; j < 8; ++j) dot[i][j] = fmaf(hv[i], cv[j], dot[i][j]);
      }
      __syncthreads();
    }
#pragma unroll
    for (int j = 0; j < 8; ++j) {
      int cl = c0 + (ct << 2) + ((j >> 2) << 7) + (j & 3);
      float cc2 = c2f[cl];
#pragma unroll
      for (int i = 0; i < 8; ++i) {
        float A = h2r[i] + cc2;
        float s = A - 2.0f * dot[i][j];
        if (s < best[i]) { best[i] = s; besti[i] = cl; }
      }
    }
  }
#pragma unroll
  for (int i = 0; i < 8; ++i) {
    float b1 = best[i]; int i1 = besti[i];
#pragma unroll
    for (int m = 16; m; m >>= 1) {
      float so = __shfl_xor(b1, m, 64);
      int io = __shfl_xor(i1, m, 64);
      if (so < b1 || (so == b1 && io < i1)) { b1 = so; i1 = io; }
    }
    if (ct == 0) {
      int p = p0 + pt * 4 + ((i >> 2) << 6) + (i & 3);
      bestval[sblk * NPTS + p] = b1;
      bestidx[sblk * NPTS + p] = i1;
    }
  }
}

__global__ __launch_bounds__(256) void merge2_kernel(
    const float* __restrict__ bestval, const int* __restrict__ bestidx,
    int* __restrict__ idx, float* __restrict__ out_idx_f) {
  int p = blockIdx.x * 256 + threadIdx.x;
  float v0 = bestval[p], v1 = bestval[NPTS + p];
  int i0 = bestidx[p], i1 = bestidx[NPTS + p];
  int w = (v1 < v0) ? i1 : i0;
  idx[p] = w;
  out_idx_f[p] = (float)w;
}

// ---------------- gather + finalize ----------------
__global__ __launch_bounds__(256) void gather_kernel(
    const float* __restrict__ h, const float* __restrict__ cb,
    const unsigned char* __restrict__ maskb, const int* __restrict__ idx,
    float* __restrict__ zq, float* __restrict__ partial) {
  int p = blockIdx.x * 4 + (threadIdx.x >> 6);
  int lane = threadIdx.x & 63;
  int ci = idx[p];
  float4 hv = reinterpret_cast<const float4*>(h)[p * (DIM / 4) + lane];
  float4 zv = reinterpret_cast<const float4*>(cb)[ci * (DIM / 4) + lane];
  float4 q;
  q.x = hv.x + (zv.x - hv.x);
  q.y = hv.y + (zv.y - hv.y);
  q.z = hv.z + (zv.z - hv.z);
  q.w = hv.w + (zv.w - hv.w);
  reinterpret_cast<float4*>(zq)[p * (DIM / 4) + lane] = q;
  float dx = hv.x - zv.x, dy = hv.y - zv.y, dz = hv.z - zv.z, dw = hv.w - zv.w;
  float s = (maskb[p] != 0) ? (dx * dx + dy * dy + dz * dz + dw * dw) : 0.f;
#pragma unroll
  for (int m = 32; m; m >>= 1) s += __shfl_xor(s, m, 64);
  __shared__ float bs[4];
  if (lane == 0) bs[threadIdx.x >> 6] = s;
  __syncthreads();
  if (threadIdx.x == 0) partial[blockIdx.x] = bs[0] + bs[1] + bs[2] + bs[3];
}

__global__ __launch_bounds__(256) void finalize_kernel(
    const float* __restrict__ partial, const unsigned char* __restrict__ maskb,
    float* __restrict__ out_losses) {
  __shared__ float red[256];
  __shared__ int redi[256];
  float s = 0.f;
  for (int i = threadIdx.x; i < NPTS / 4; i += 256) s += partial[i];
  int cnt = 0;
  for (int i = threadIdx.x; i < NPTS; i += 256) cnt += (maskb[i] != 0);
  red[threadIdx.x] = s;
  redi[threadIdx.x] = cnt;
  __syncthreads();
  for (int step = 128; step; step >>= 1) {
    if (threadIdx.x < step) {
      red[threadIdx.x] += red[threadIdx.x + step];
      redi[threadIdx.x] += redi[threadIdx.x + step];
    }
    __syncthreads();
  }
  if (threadIdx.x == 0) {
    float denom = (float)redi[0] * (float)DIM + 1e-8f;
    float loss = red[0] / denom;
    out_losses[0] = loss;
    out_losses[1] = loss;
  }
}

extern "C" void kernel_launch(void* const* d_in, const int* in_sizes, int n_in,
                              void* d_out, int out_size, void* d_ws, size_t ws_size,
                              hipStream_t stream) {
  const float* h = (const float*)d_in[0];
  const unsigned char* maskb = (const unsigned char*)d_in[1];
  const float* cb = (const float*)d_in[2];

  float* out = (float*)d_out;
  float* zq = out;
  float* out_idx_f = out + NPTS * DIM;
  float* out_losses = out + NPTS * DIM + NPTS;

  char* ws = (char*)d_ws;
  const size_t REQ = 44040192ULL;  // 42 MB

  if (ws_size >= REQ) {
    float* h2f = (float*)(ws + 0);                    // 128K
    float* c2f = (float*)(ws + 131072);               // 32K
    float* bv = (float*)(ws + 163840);                // 512K
    int* bi = (int*)(ws + 688128);                    // 512K
    float* b2o = (float*)(ws + 1212416);              // 512K
    int* idx = (int*)(ws + 1736704);                  // 128K
    float* partial = (float*)(ws + 1867776);          // 32K
    int* flagcnt = (int*)(ws + 1900544);              // 4 (+pad)
    int* flaglist = (int*)(ws + 1904640);             // 128K
    unsigned short* hh = (unsigned short*)(ws + 2097152);    // 16M
    unsigned short* hl = (unsigned short*)(ws + 18874368);   // 16M
    unsigned short* chh = (unsigned short*)(ws + 35651584);  // 4M
    unsigned short* cll = (unsigned short*)(ws + 39845888);  // 4M

    hipLaunchKernelGGL(split_norms_kernel, dim3(NPTS / 4), dim3(256), 0, stream,
                       h, hh, hl, h2f, flagcnt);
    hipLaunchKernelGGL(split_norms_kernel, dim3(KCODES / 4), dim3(256), 0, stream,
                       cb, chh, cll, c2f, (int*)nullptr);
    hipLaunchKernelGGL(mfma_argmin_kernel, dim3(512), dim3(512), 0, stream,
                       hh, hl, chh, cll, h2f, c2f, bv, bi, b2o);
    hipLaunchKernelGGL(merge_flag_kernel, dim3(NPTS / 256), dim3(256), 0, stream,
                       bv, bi, b2o, idx, out_idx_f, flagcnt, flaglist);
    hipLaunchKernelGGL(refine_kernel, dim3(512), dim3(256), 0, stream,
                       h, cb, h2f, c2f, flagcnt, flaglist, idx, out_idx_f);
    hipLaunchKernelGGL(gather_kernel, dim3(NPTS / 4), dim3(256), 0, stream,
                       h, cb, maskb, idx, zq, partial);
    hipLaunchKernelGGL(finalize_kernel, dim3(1), dim3(256), 0, stream,
                       partial, maskb, out_losses);
  } else {
    float* h2f = (float*)(ws + 0);
    float* c2f = (float*)(ws + (128 << 10));
    float* bestval = (float*)(ws + (160 << 10));
    int* bestidx = (int*)(ws + (416 << 10));
    int* idx = (int*)(ws + (672 << 10));
    float* partial = (float*)(ws + (800 << 10));

    hipLaunchKernelGGL(norms_kernel, dim3(NPTS / 4), dim3(256), 0, stream, h, h2f);
    hipLaunchKernelGGL(norms_kernel, dim3(KCODES / 4), dim3(256), 0, stream, cb, c2f);
    hipLaunchKernelGGL(argmin_fp32_kernel, dim3(512), dim3(512), 0, stream,
                       h, cb, h2f, c2f, bestval, bestidx);
    hipLaunchKernelGGL(merge2_kernel, dim3(NPTS / 256), dim3(256), 0, stream,
                       bestval, bestidx, idx, out_idx_f);
    hipLaunchKernelGGL(gather_kernel, dim3(NPTS / 4), dim3(256), 0, stream,
                       h, cb, maskb, idx, zq, partial);
    hipLaunchKernelGGL(finalize_kernel, dim3(1), dim3(256), 0, stream,
                       partial, maskb, out_losses);
  }
}